// Round 15
// baseline (287.327 us; speedup 1.0000x reference)
//
#include <hip/hip_runtime.h>

#define B_N 131072
#define IN_N 40
#define H_N 256

typedef __bf16 bf16x8 __attribute__((ext_vector_type(8)));
typedef float f32x4 __attribute__((ext_vector_type(4)));

#define MFMA(a, b, c) __builtin_amdgcn_mfma_f32_16x16x32_bf16(a, b, c, 0, 0, 0)

// ws bf16 layout (identical to v13/v14 — verified):
//   quarter q (64 hcols): gh [3 g][8 ks][4 sub][64 col][8 e]   (49152 elems)
//                         gi [3 g][2 ks][4 sub][64 col][8 e]   (12288 elems)
//   k = ks*32 + sub*8 + e; col = block-local hcol; gi zero for k>=40
// then f32 bfused[768] = b_ih + W_ih@b_proj
#define WSQ 61440
#define WSBI (4 * WSQ)                    // 245760
#define PREP_N (245760 + 768 + B_N)

__global__ void prep(const float* __restrict__ Wp, const float* __restrict__ bp,
                     const float* __restrict__ Wih, const float* __restrict__ Whh,
                     const float* __restrict__ bih, const float* __restrict__ bhead,
                     __bf16* __restrict__ wsb, float* __restrict__ out) {
  int i = blockIdx.x * 256 + threadIdx.x;
  if (i < WSBI) {
    const int quarter = i / WSQ, r = i % WSQ;
    if (r < 49152) {  // gh
      const int g = r >> 14, ks = (r >> 11) & 7, sub = (r >> 9) & 3,
                col = (r >> 3) & 63, e = r & 7;
      const int gatecol = g * 256 + quarter * 64 + col;
      const int k = ks * 32 + sub * 8 + e;
      wsb[i] = (__bf16)Whh[(size_t)gatecol * 256 + k];
    } else {          // gi (fused)
      const int rr = r - 49152;
      const int g = rr >> 12, ks = (rr >> 11) & 1, sub = (rr >> 9) & 3,
                col = (rr >> 3) & 63, e = rr & 7;
      const int gatecol = g * 256 + quarter * 64 + col;
      const int k = ks * 32 + sub * 8 + e;
      float v = 0.f;
      if (k < IN_N)
        for (int p = 0; p < 128; ++p)
          v += Wih[(size_t)gatecol * 128 + p] * Wp[p * IN_N + k];
      wsb[i] = (__bf16)v;
    }
  } else if (i < WSBI + 768) {
    const int g = i - WSBI;
    float v = bih[g];
    for (int p = 0; p < 128; ++p) v += Wih[g * 128 + p] * bp[p];
    ((float*)(wsb + WSBI))[g] = v;
  } else if (i < PREP_N) {
    out[i - (WSBI + 768)] = bhead[0];  // pred init = bias; waves atomicAdd partials
  }
}

__device__ __forceinline__ void gload16(const __bf16* g, __bf16* l) {
  __builtin_amdgcn_global_load_lds(
      (const __attribute__((address_space(1))) void*)g,
      (__attribute__((address_space(3))) void*)l, 16, 0, 0);
}

__device__ __forceinline__ bf16x8 cvt8(float4 a, float4 b) {
  bf16x8 u;
  u[0] = (__bf16)a.x; u[1] = (__bf16)a.y; u[2] = (__bf16)a.z; u[3] = (__bf16)a.w;
  u[4] = (__bf16)b.x; u[5] = (__bf16)b.y; u[6] = (__bf16)b.z; u[7] = (__bf16)b.w;
  return u;
}

// fast gate math: v_exp_f32 is exp2; rcp instead of divide
__device__ __forceinline__ float fsig(float v) {
  return __builtin_amdgcn_rcpf(1.f + __builtin_amdgcn_exp2f(-1.44269504f * v));
}
__device__ __forceinline__ float ftanh(float u) {
  return 2.f * __builtin_amdgcn_rcpf(1.f + __builtin_amdgcn_exp2f(-2.88539008f * u)) - 1.f;
}

// 1024 blocks = 4 quarters x 256 row-groups; 1024 thr = 16 waves (4rw x 4cw).
// Persistent: block stages gh weights (96KB LDS) once, then 4 tiles of 128 rows.
// Wave = 32 rows x 16 cols (Mr=2: 5 LDS reads per 6 MFMA). gi weights live in
// 24 regs/wave; gi A-frags straight from global x. h-tile 64KB LDS swizzled.
__global__ __launch_bounds__(1024, 1) void gru_v17(
    const float* __restrict__ x, const float* __restrict__ h0,
    const __bf16* __restrict__ wsb, const float* __restrict__ bhh,
    const float* __restrict__ Whead, float* __restrict__ out) {
  __shared__ __bf16 WG[49152];    //  98304 B: gh [3][8][4][64][8]
  __shared__ __bf16 hsw[32768];   //  65536 B: [128 row][32 ci ^ (row&7)][8]
                                  //  total 163840 B = 160 KiB exact

  const int tid = threadIdx.x;
  const int lane = tid & 63;
  const int w = tid >> 6;              // 0..15
  const int l15 = lane & 15;
  const int l4 = lane >> 4;
  const int rw = w >> 2, cw = w & 3;

  // XCD-chunked: 4 quarter-siblings + consecutive row-groups per XCD
  const int lin = (blockIdx.x & 7) * 128 + (blockIdx.x >> 3);
  const int quarter = lin & 3;
  const size_t row0 = (size_t)(lin >> 2) * 512;

  const int colB = cw * 16 + l15;      // block-local hcol 0..63
  const int hcol = quarter * 64 + colB;

  // ---- stage gh weights to LDS once (96 x 1KB async copies) ----
  const __bf16* wsq = wsb + quarter * WSQ;
#pragma unroll
  for (int j = 0; j < 6; ++j) {
    const int idx = w * 6 + j;         // wave-uniform, 0..95
    gload16(wsq + idx * 512 + lane * 8, &WG[idx * 512]);
  }

  // ---- gi weights -> registers (per-wave cols, whole-block lifetime) ----
  bf16x8 giW[3][2];
#pragma unroll
  for (int g = 0; g < 3; ++g)
#pragma unroll
    for (int ks = 0; ks < 2; ++ks)
      giW[g][ks] = *reinterpret_cast<const bf16x8*>(
          wsq + 49152 + ((g * 2 + ks) * 4 + l4) * 512 + colB * 8);

  const float* bfused = (const float*)(wsb + WSBI);
  const float bR = bfused[hcol] + bhh[hcol];
  const float bZ = bfused[256 + hcol] + bhh[256 + hcol];
  const float bI = bfused[512 + hcol];
  const float bH = bhh[512 + hcol];
  const float wh = Whead[hcol];

  // ---- h staging: global -> reg (cvt at arrival, 16 VGPR) -> LDS ----
  bf16x8 hreg[4];
  auto issueH = [&](int t) {
    const float* hb = h0 + (row0 + (size_t)t * 128) * H_N;
#pragma unroll
    for (int j = 0; j < 4; ++j) {
      const int c = tid + j * 1024;    // chunk 0..4095: row=c>>5, ci=c&31
      const float* s = hb + (size_t)(c >> 5) * H_N + (c & 31) * 8;
      hreg[j] = cvt8(*reinterpret_cast<const float4*>(s),
                     *reinterpret_cast<const float4*>(s + 4));
    }
  };
  auto writeH = [&]() {
#pragma unroll
    for (int j = 0; j < 4; ++j) {
      const int c = tid + j * 1024;
      const int row = c >> 5, ci = c & 31;
      *reinterpret_cast<bf16x8*>(&hsw[row * 256 + ((ci ^ (row & 7)) << 3)]) = hreg[j];
    }
  };

  issueH(0);
  writeH();
  __syncthreads();   // weights (vmcnt drained) + h tile 0 visible

  for (int t = 0; t < 4; ++t) {
    const size_t trow = row0 + (size_t)t * 128;

    // acc init (Mr=2)
    f32x4 aR[2], aZ[2], aI[2], aH4[2];
#pragma unroll
    for (int mi = 0; mi < 2; ++mi) {
      aR[mi] = (f32x4){bR, bR, bR, bR};
      aZ[mi] = (f32x4){bZ, bZ, bZ, bZ};
      aI[mi] = (f32x4){bI, bI, bI, bI};
      aH4[mi] = (f32x4){bH, bH, bH, bH};
    }

    // ---- gi: A from global x (rows 160B-strided), B from regs ----
#pragma unroll
    for (int ks = 0; ks < 2; ++ks) {
#pragma unroll
      for (int mi = 0; mi < 2; ++mi) {
        bf16x8 a;
        if (ks == 0 || l4 == 0) {      // ks=1,l4>0 would read k>=40 (OOB; W=0)
          const float* s = x + (trow + rw * 32 + mi * 16 + l15) * IN_N
                             + ks * 32 + l4 * 8;
          a = cvt8(*reinterpret_cast<const float4*>(s),
                   *reinterpret_cast<const float4*>(s + 4));
        } else {
          a = (bf16x8){};
        }
        aR[mi] = MFMA(a, giW[0][ks], aR[mi]);
        aZ[mi] = MFMA(a, giW[1][ks], aZ[mi]);
        aI[mi] = MFMA(a, giW[2][ks], aI[mi]);
      }
    }

    if (t < 3) issueH(t + 1);   // T14: next h tile global->reg under gh compute

    // ---- gh: A from hsw (swizzled), B from WG ----
    const int bofs = l4 * 512 + colB * 8;
#pragma unroll
    for (int ks = 0; ks < 8; ++ks) {
      const bf16x8 b0 = *reinterpret_cast<const bf16x8*>(&WG[(0 + ks) * 2048 + bofs]);
      const bf16x8 b1 = *reinterpret_cast<const bf16x8*>(&WG[(8 + ks) * 2048 + bofs]);
      const bf16x8 b2 = *reinterpret_cast<const bf16x8*>(&WG[(16 + ks) * 2048 + bofs]);
#pragma unroll
      for (int mi = 0; mi < 2; ++mi) {
        const int arow = rw * 32 + mi * 16 + l15;
        const bf16x8 a = *reinterpret_cast<const bf16x8*>(
            &hsw[arow * 256 + (((ks * 4 + l4) ^ (arow & 7)) << 3)]);
        aR[mi] = MFMA(a, b0, aR[mi]);
        aZ[mi] = MFMA(a, b1, aZ[mi]);
        aH4[mi] = MFMA(a, b2, aH4[mi]);
      }
    }

    __syncthreads();            // all hsw reads of tile t done

    if (t < 3) writeH();        // ds_writes overlap epilogue VALU below

    // ---- epilogue: fast gates, h_new store, pred partials; hv from h0 ----
    float ps[2][4];
#pragma unroll
    for (int mi = 0; mi < 2; ++mi) {
#pragma unroll
      for (int r = 0; r < 4; ++r) {
        const int rowl = rw * 32 + mi * 16 + l4 * 4 + r;
        const float rg = fsig(aR[mi][r]);
        const float zg = fsig(aZ[mi][r]);
        const float ng = ftanh(aI[mi][r] + rg * aH4[mi][r]);
        const float hv = h0[(trow + rowl) * H_N + hcol];   // L1/L2-hot
        const float hn = (1.f - zg) * ng + zg * hv;
        out[(size_t)B_N + (trow + rowl) * H_N + hcol] = hn;
        ps[mi][r] = hn * wh;
      }
    }
#pragma unroll
    for (int mi = 0; mi < 2; ++mi)
#pragma unroll
      for (int r = 0; r < 4; ++r) {
        float s = ps[mi][r];
        s += __shfl_xor(s, 1);
        s += __shfl_xor(s, 2);
        s += __shfl_xor(s, 4);
        s += __shfl_xor(s, 8);
        if (l15 == 0)
          atomicAdd(&out[trow + rw * 32 + mi * 16 + l4 * 4 + r], s);
      }

    if (t < 3) __syncthreads();  // staged hsw(t+1) visible before next gh reads
  }
}

extern "C" void kernel_launch(void* const* d_in, const int* in_sizes, int n_in,
                              void* d_out, int out_size, void* d_ws, size_t ws_size,
                              hipStream_t stream) {
  const float* x     = (const float*)d_in[0];
  const float* h0    = (const float*)d_in[1];
  const float* Wp    = (const float*)d_in[2];
  const float* bp    = (const float*)d_in[3];
  const float* Wih   = (const float*)d_in[4];
  const float* Whh   = (const float*)d_in[5];
  const float* bih   = (const float*)d_in[6];
  const float* bhh   = (const float*)d_in[7];
  const float* Whead = (const float*)d_in[8];
  const float* bhead = (const float*)d_in[9];
  float* out = (float*)d_out;
  __bf16* wsb = (__bf16*)d_ws;

  prep<<<(PREP_N + 255) / 256, 256, 0, stream>>>(Wp, bp, Wih, Whh, bih, bhead, wsb, out);
  gru_v17<<<1024, 1024, 0, stream>>>(x, h0, wsb, bhh, Whead, out);
}

// Round 16
// 253.342 us; speedup vs baseline: 1.1341x; 1.1341x over previous
//
#include <hip/hip_runtime.h>

#define B_N 131072
#define IN_N 40
#define H_N 256

typedef __bf16 bf16x8 __attribute__((ext_vector_type(8)));
typedef float f32x4 __attribute__((ext_vector_type(4)));

#define MFMA(a, b, c) __builtin_amdgcn_mfma_f32_16x16x32_bf16(a, b, c, 0, 0, 0)

// ws bf16 layout (identical to v13/v14/v17 — verified):
//   quarter q (64 hcols): gh [3 g][8 ks][4 sub][64 col][8 e]   (49152 elems)
//                         gi [3 g][2 ks][4 sub][64 col][8 e]   (12288 elems)
//   k = ks*32 + sub*8 + e; col = block-local hcol; gi zero for k>=40
// then f32 bfused[768] = b_ih + W_ih@b_proj
#define WSQ 61440
#define WSBI (4 * WSQ)                    // 245760
#define PREP_N (245760 + 768 + B_N)

__global__ void prep(const float* __restrict__ Wp, const float* __restrict__ bp,
                     const float* __restrict__ Wih, const float* __restrict__ Whh,
                     const float* __restrict__ bih, const float* __restrict__ bhead,
                     __bf16* __restrict__ wsb, float* __restrict__ out) {
  int i = blockIdx.x * 256 + threadIdx.x;
  if (i < WSBI) {
    const int quarter = i / WSQ, r = i % WSQ;
    if (r < 49152) {  // gh
      const int g = r >> 14, ks = (r >> 11) & 7, sub = (r >> 9) & 3,
                col = (r >> 3) & 63, e = r & 7;
      const int gatecol = g * 256 + quarter * 64 + col;
      const int k = ks * 32 + sub * 8 + e;
      wsb[i] = (__bf16)Whh[(size_t)gatecol * 256 + k];
    } else {          // gi (fused)
      const int rr = r - 49152;
      const int g = rr >> 12, ks = (rr >> 11) & 1, sub = (rr >> 9) & 3,
                col = (rr >> 3) & 63, e = rr & 7;
      const int gatecol = g * 256 + quarter * 64 + col;
      const int k = ks * 32 + sub * 8 + e;
      float v = 0.f;
      if (k < IN_N)
        for (int p = 0; p < 128; ++p)
          v += Wih[(size_t)gatecol * 128 + p] * Wp[p * IN_N + k];
      wsb[i] = (__bf16)v;
    }
  } else if (i < WSBI + 768) {
    const int g = i - WSBI;
    float v = bih[g];
    for (int p = 0; p < 128; ++p) v += Wih[g * 128 + p] * bp[p];
    ((float*)(wsb + WSBI))[g] = v;
  } else if (i < PREP_N) {
    out[i - (WSBI + 768)] = bhead[0];  // pred init = bias; waves atomicAdd partials
  }
}

__device__ __forceinline__ void gload16(const __bf16* g, __bf16* l) {
  __builtin_amdgcn_global_load_lds(
      (const __attribute__((address_space(1))) void*)g,
      (__attribute__((address_space(3))) void*)l, 16, 0, 0);
}

__device__ __forceinline__ bf16x8 cvt8(float4 a, float4 b) {
  bf16x8 u;
  u[0] = (__bf16)a.x; u[1] = (__bf16)a.y; u[2] = (__bf16)a.z; u[3] = (__bf16)a.w;
  u[4] = (__bf16)b.x; u[5] = (__bf16)b.y; u[6] = (__bf16)b.z; u[7] = (__bf16)b.w;
  return u;
}

// fast gate math: v_exp_f32 computes 2^x; rcp instead of divide
__device__ __forceinline__ float fsig(float v) {
  return __builtin_amdgcn_rcpf(1.f + __builtin_amdgcn_exp2f(-1.44269504f * v));
}
__device__ __forceinline__ float ftanh(float u) {
  return 2.f * __builtin_amdgcn_rcpf(1.f + __builtin_amdgcn_exp2f(-2.88539008f * u)) - 1.f;
}

// 1024 blocks = 4 quarters x 256 row-groups; 1024 thr = 16 waves (4rw x 4cw).
// Persistent: block stages gh weights (96KB LDS) once, then 4 tiles of 128 rows.
// Wave = 32 rows x 16 cols (Mr=2). gi weights loaded per tile (TRANSIENT — the
// v17 spill fix); gi A-frags straight from global x. h-tile 64KB LDS swizzled.
__global__ __launch_bounds__(1024, 1) void gru_v18(
    const float* __restrict__ x, const float* __restrict__ h0,
    const __bf16* __restrict__ wsb, const float* __restrict__ bhh,
    const float* __restrict__ Whead, float* __restrict__ out) {
  __shared__ __bf16 WG[49152];    //  98304 B: gh [3][8][4][64][8]
  __shared__ __bf16 hsw[32768];   //  65536 B: [128 row][32 ci ^ (row&7)][8]
                                  //  total 163840 B = 160 KiB exact

  const int tid = threadIdx.x;
  const int lane = tid & 63;
  const int w = tid >> 6;              // 0..15
  const int l15 = lane & 15;
  const int l4 = lane >> 4;
  const int rw = w >> 2, cw = w & 3;

  // XCD-chunked: 4 quarter-siblings + consecutive row-groups per XCD
  const int lin = (blockIdx.x & 7) * 128 + (blockIdx.x >> 3);
  const int quarter = lin & 3;
  const size_t row0 = (size_t)(lin >> 2) * 512;

  const int colB = cw * 16 + l15;      // block-local hcol 0..63
  const int hcol = quarter * 64 + colB;

  // ---- stage gh weights to LDS once (96 x 1KB async copies) ----
  const __bf16* wsq = wsb + quarter * WSQ;
#pragma unroll
  for (int j = 0; j < 6; ++j) {
    const int idx = w * 6 + j;         // wave-uniform, 0..95
    gload16(wsq + idx * 512 + lane * 8, &WG[idx * 512]);
  }
  const __bf16* giWp = wsq + 49152 + l4 * 512 + colB * 8;  // + (g*2+ks)*2048

  const float* bfused = (const float*)(wsb + WSBI);
  const float bR = bfused[hcol] + bhh[hcol];
  const float bZ = bfused[256 + hcol] + bhh[256 + hcol];
  const float bI = bfused[512 + hcol];
  const float bH = bhh[512 + hcol];
  const float wh = Whead[hcol];

  // ---- h staging: global -> reg (cvt at arrival, 16 VGPR) -> LDS ----
  bf16x8 hreg[4];
  auto issueH = [&](int t) {
    const float* hb = h0 + (row0 + (size_t)t * 128) * H_N;
#pragma unroll
    for (int j = 0; j < 4; ++j) {
      const int c = tid + j * 1024;    // chunk 0..4095: row=c>>5, ci=c&31
      const float* s = hb + (size_t)(c >> 5) * H_N + (c & 31) * 8;
      hreg[j] = cvt8(*reinterpret_cast<const float4*>(s),
                     *reinterpret_cast<const float4*>(s + 4));
    }
  };
  auto writeH = [&]() {
#pragma unroll
    for (int j = 0; j < 4; ++j) {
      const int c = tid + j * 1024;
      const int row = c >> 5, ci = c & 31;
      *reinterpret_cast<bf16x8*>(&hsw[row * 256 + ((ci ^ (row & 7)) << 3)]) = hreg[j];
    }
  };

  issueH(0);
  writeH();
  __syncthreads();   // weights (vmcnt drained) + h tile 0 visible

  for (int t = 0; t < 4; ++t) {
    const size_t trow = row0 + (size_t)t * 128;

    // acc init (Mr=2)
    f32x4 aR[2], aZ[2], aI[2], aH4[2];
#pragma unroll
    for (int mi = 0; mi < 2; ++mi) {
      aR[mi] = (f32x4){bR, bR, bR, bR};
      aZ[mi] = (f32x4){bZ, bZ, bZ, bZ};
      aI[mi] = (f32x4){bI, bI, bI, bI};
      aH4[mi] = (f32x4){bH, bH, bH, bH};
    }

    // ---- gi: A from global x, B from global (L2-hot, TRANSIENT regs) ----
#pragma unroll
    for (int ks = 0; ks < 2; ++ks) {
      const bf16x8 g0 = *reinterpret_cast<const bf16x8*>(giWp + (0 * 2 + ks) * 2048);
      const bf16x8 g1 = *reinterpret_cast<const bf16x8*>(giWp + (1 * 2 + ks) * 2048);
      const bf16x8 g2 = *reinterpret_cast<const bf16x8*>(giWp + (2 * 2 + ks) * 2048);
#pragma unroll
      for (int mi = 0; mi < 2; ++mi) {
        bf16x8 a;
        if (ks == 0 || l4 == 0) {      // ks=1,l4>0 would read k>=40 (W=0 there)
          const float* s = x + (trow + rw * 32 + mi * 16 + l15) * IN_N
                             + ks * 32 + l4 * 8;
          a = cvt8(*reinterpret_cast<const float4*>(s),
                   *reinterpret_cast<const float4*>(s + 4));
        } else {
          a = (bf16x8){};
        }
        aR[mi] = MFMA(a, g0, aR[mi]);
        aZ[mi] = MFMA(a, g1, aZ[mi]);
        aI[mi] = MFMA(a, g2, aI[mi]);
      }
    }

    if (t < 3) issueH(t + 1);   // T14: next h tile global->reg under gh compute

    // ---- gh: A from hsw (swizzled), B from WG ----
    const int bofs = l4 * 512 + colB * 8;
#pragma unroll
    for (int ks = 0; ks < 8; ++ks) {
      const bf16x8 b0 = *reinterpret_cast<const bf16x8*>(&WG[(0 + ks) * 2048 + bofs]);
      const bf16x8 b1 = *reinterpret_cast<const bf16x8*>(&WG[(8 + ks) * 2048 + bofs]);
      const bf16x8 b2 = *reinterpret_cast<const bf16x8*>(&WG[(16 + ks) * 2048 + bofs]);
#pragma unroll
      for (int mi = 0; mi < 2; ++mi) {
        const int arow = rw * 32 + mi * 16 + l15;
        const bf16x8 a = *reinterpret_cast<const bf16x8*>(
            &hsw[arow * 256 + (((ks * 4 + l4) ^ (arow & 7)) << 3)]);
        aR[mi] = MFMA(a, b0, aR[mi]);
        aZ[mi] = MFMA(a, b1, aZ[mi]);
        aH4[mi] = MFMA(a, b2, aH4[mi]);
      }
    }

    __syncthreads();            // all hsw reads of tile t done

    if (t < 3) writeH();        // ds_writes overlap epilogue VALU below

    // ---- epilogue: fast gates, h_new store, pred partials; hv from h0 ----
    float ps[2][4];
#pragma unroll
    for (int mi = 0; mi < 2; ++mi) {
#pragma unroll
      for (int r = 0; r < 4; ++r) {
        const int rowl = rw * 32 + mi * 16 + l4 * 4 + r;
        const float rg = fsig(aR[mi][r]);
        const float zg = fsig(aZ[mi][r]);
        const float ng = ftanh(aI[mi][r] + rg * aH4[mi][r]);
        const float hv = h0[(trow + rowl) * H_N + hcol];   // L1/L2-hot
        const float hn = (1.f - zg) * ng + zg * hv;
        out[(size_t)B_N + (trow + rowl) * H_N + hcol] = hn;
        ps[mi][r] = hn * wh;
      }
    }
#pragma unroll
    for (int mi = 0; mi < 2; ++mi)
#pragma unroll
      for (int r = 0; r < 4; ++r) {
        float s = ps[mi][r];
        s += __shfl_xor(s, 1);
        s += __shfl_xor(s, 2);
        s += __shfl_xor(s, 4);
        s += __shfl_xor(s, 8);
        if (l15 == 0)
          atomicAdd(&out[trow + rw * 32 + mi * 16 + l4 * 4 + r], s);
      }

    if (t < 3) __syncthreads();  // staged hsw(t+1) visible before next gh reads
  }
}

extern "C" void kernel_launch(void* const* d_in, const int* in_sizes, int n_in,
                              void* d_out, int out_size, void* d_ws, size_t ws_size,
                              hipStream_t stream) {
  const float* x     = (const float*)d_in[0];
  const float* h0    = (const float*)d_in[1];
  const float* Wp    = (const float*)d_in[2];
  const float* bp    = (const float*)d_in[3];
  const float* Wih   = (const float*)d_in[4];
  const float* Whh   = (const float*)d_in[5];
  const float* bih   = (const float*)d_in[6];
  const float* bhh   = (const float*)d_in[7];
  const float* Whead = (const float*)d_in[8];
  const float* bhead = (const float*)d_in[9];
  float* out = (float*)d_out;
  __bf16* wsb = (__bf16*)d_ws;

  prep<<<(PREP_N + 255) / 256, 256, 0, stream>>>(Wp, bp, Wih, Whh, bih, bhead, wsb, out);
  gru_v18<<<1024, 1024, 0, stream>>>(x, h0, wsb, bhh, Whead, out);
}

// Round 17
// 245.759 us; speedup vs baseline: 1.1691x; 1.0309x over previous
//
#include <hip/hip_runtime.h>

#define B_N 131072
#define IN_N 40
#define H_N 256

typedef __bf16 bf16x8 __attribute__((ext_vector_type(8)));
typedef float f32x16 __attribute__((ext_vector_type(16)));

#define MFMA32(a, b, c) __builtin_amdgcn_mfma_f32_32x32x16_bf16(a, b, c, 0, 0, 0)

// ws bf16 layout (identical image to v13..v18 — verified):
//   quarter q (64 hcols): gh [3 g][8 ks][4 sub][64 col][8 e]   (49152 elems)
//                         gi [3 g][2 ks][4 sub][64 col][8 e]   (12288 elems)
//   k = ks*32 + sub*8 + e  ==  flat idx = k/8 in [0,32) :
//   offset = (gate*{32|8} + idx)*512 + col*8   — works for 16-wide K-steps too.
// then f32 bfused[768] = b_ih + W_ih@b_proj
#define WSQ 61440
#define WSBI (4 * WSQ)                    // 245760
#define PREP_N (245760 + 768 + B_N)

__global__ void prep(const float* __restrict__ Wp, const float* __restrict__ bp,
                     const float* __restrict__ Wih, const float* __restrict__ Whh,
                     const float* __restrict__ bih, const float* __restrict__ bhead,
                     __bf16* __restrict__ wsb, float* __restrict__ out) {
  int i = blockIdx.x * 256 + threadIdx.x;
  if (i < WSBI) {
    const int quarter = i / WSQ, r = i % WSQ;
    if (r < 49152) {  // gh
      const int g = r >> 14, ks = (r >> 11) & 7, sub = (r >> 9) & 3,
                col = (r >> 3) & 63, e = r & 7;
      const int gatecol = g * 256 + quarter * 64 + col;
      const int k = ks * 32 + sub * 8 + e;
      wsb[i] = (__bf16)Whh[(size_t)gatecol * 256 + k];
    } else {          // gi (fused)
      const int rr = r - 49152;
      const int g = rr >> 12, ks = (rr >> 11) & 1, sub = (rr >> 9) & 3,
                col = (rr >> 3) & 63, e = rr & 7;
      const int gatecol = g * 256 + quarter * 64 + col;
      const int k = ks * 32 + sub * 8 + e;
      float v = 0.f;
      if (k < IN_N)
        for (int p = 0; p < 128; ++p)
          v += Wih[(size_t)gatecol * 128 + p] * Wp[p * IN_N + k];
      wsb[i] = (__bf16)v;
    }
  } else if (i < WSBI + 768) {
    const int g = i - WSBI;
    float v = bih[g];
    for (int p = 0; p < 128; ++p) v += Wih[g * 128 + p] * bp[p];
    ((float*)(wsb + WSBI))[g] = v;
  } else if (i < PREP_N) {
    out[i - (WSBI + 768)] = bhead[0];  // pred init = bias; waves atomicAdd partials
  }
}

__device__ __forceinline__ void gload16(const __bf16* g, __bf16* l) {
  __builtin_amdgcn_global_load_lds(
      (const __attribute__((address_space(1))) void*)g,
      (__attribute__((address_space(3))) void*)l, 16, 0, 0);
}

__device__ __forceinline__ bf16x8 cvt8(float4 a, float4 b) {
  bf16x8 u;
  u[0] = (__bf16)a.x; u[1] = (__bf16)a.y; u[2] = (__bf16)a.z; u[3] = (__bf16)a.w;
  u[4] = (__bf16)b.x; u[5] = (__bf16)b.y; u[6] = (__bf16)b.z; u[7] = (__bf16)b.w;
  return u;
}

// fast gate math: v_exp_f32 computes 2^x; rcp instead of divide
__device__ __forceinline__ float fsig(float v) {
  return __builtin_amdgcn_rcpf(1.f + __builtin_amdgcn_exp2f(-1.44269504f * v));
}
__device__ __forceinline__ float ftanh(float u) {
  return 2.f * __builtin_amdgcn_rcpf(1.f + __builtin_amdgcn_exp2f(-2.88539008f * u)) - 1.f;
}

// 1024 blocks = 4 quarters x 256 row-groups; 512 thr = 8 waves (4rw x 2cw).
// 32x32x16 MFMA: wave = 32 rows x 32 cols; per K-step 4 ds_read_b128 feed
// 3 MFMAs of 32KFLOP (half the LDS traffic/FLOP of 16x16x32).
// Persistent: gh weights (96KB) staged to LDS once; 4 tiles of 128 rows;
// h-tile 64KB swizzled; gi A/B from global (transient regs). 2 barriers/tile.
__global__ __launch_bounds__(512, 1) void gru_v19(
    const float* __restrict__ x, const float* __restrict__ h0,
    const __bf16* __restrict__ wsb, const float* __restrict__ bhh,
    const float* __restrict__ Whead, float* __restrict__ out) {
  __shared__ __bf16 WG[49152];    //  98304 B: gh [3][32 idx][64 col][8]
  __shared__ __bf16 hsw[32768];   //  65536 B: [128 row][32 ci ^ (row&7)][8]
                                  //  total 163840 B = 160 KiB exact

  const int tid = threadIdx.x;
  const int lane = tid & 63;
  const int w = tid >> 6;              // 0..7
  const int l31 = lane & 31;
  const int kh = lane >> 5;            // fragment k-half
  const int rw = w >> 1, cw = w & 1;   // 4 row-bands x 2 col-halves

  // XCD-chunked: 4 quarter-siblings + consecutive row-groups per XCD
  const int lin = (blockIdx.x & 7) * 128 + (blockIdx.x >> 3);
  const int quarter = lin & 3;
  const size_t row0 = (size_t)(lin >> 2) * 512;

  const int colB = cw * 32 + l31;      // block-local hcol 0..63
  const int hcol = quarter * 64 + colB;

  // ---- stage gh weights to LDS once (96 x 1KB async copies) ----
  const __bf16* wsq = wsb + quarter * WSQ;
#pragma unroll
  for (int j = 0; j < 12; ++j) {
    const int idx = w * 12 + j;        // wave-uniform, 0..95
    gload16(wsq + idx * 512 + lane * 8, &WG[idx * 512]);
  }
  const __bf16* giWp = wsq + 49152 + colB * 8;  // + (g*8 + ks16*2 + kh)*512

  const float* bfused = (const float*)(wsb + WSBI);
  const float bR = bfused[hcol] + bhh[hcol];
  const float bZ = bfused[256 + hcol] + bhh[256 + hcol];
  const float bI = bfused[512 + hcol];
  const float bH = bhh[512 + hcol];
  const float wh = Whead[hcol];

  // ---- h staging: global -> reg (cvt at arrival, 32 VGPR) -> LDS ----
  bf16x8 hreg[8];
  auto issueH = [&](int t) {
    const float* hb = h0 + (row0 + (size_t)t * 128) * H_N;
#pragma unroll
    for (int j = 0; j < 8; ++j) {
      const int c = tid + j * 512;     // chunk 0..4095: row=c>>5, ci=c&31
      const float* s = hb + (size_t)(c >> 5) * H_N + (c & 31) * 8;
      hreg[j] = cvt8(*reinterpret_cast<const float4*>(s),
                     *reinterpret_cast<const float4*>(s + 4));
    }
  };
  auto writeH = [&]() {
#pragma unroll
    for (int j = 0; j < 8; ++j) {
      const int c = tid + j * 512;
      const int row = c >> 5, ci = c & 31;
      *reinterpret_cast<bf16x8*>(&hsw[row * 256 + ((ci ^ (row & 7)) << 3)]) = hreg[j];
    }
  };

  issueH(0);
  writeH();
  __syncthreads();   // weights (vmcnt drained at barrier) + h tile 0 visible

  for (int t = 0; t < 4; ++t) {
    const size_t trow = row0 + (size_t)t * 128;

    f32x16 aR = {}, aZ = {}, aI = {}, aH4 = {};
#pragma unroll
    for (int r = 0; r < 16; ++r) {
      aR[r] = bR; aZ[r] = bZ; aI[r] = bI; aH4[r] = bH;
    }

    // ---- gi: K-steps 0..2 (k 0..47; k>=40 has W=0, A zeroed) ----
#pragma unroll
    for (int ks = 0; ks < 3; ++ks) {
      const int idx = ks * 2 + kh;     // flat 8-elem k-chunk index
      const bf16x8 g0 = *reinterpret_cast<const bf16x8*>(giWp + (0 * 8 + idx) * 512);
      const bf16x8 g1 = *reinterpret_cast<const bf16x8*>(giWp + (1 * 8 + idx) * 512);
      const bf16x8 g2 = *reinterpret_cast<const bf16x8*>(giWp + (2 * 8 + idx) * 512);
      bf16x8 a;
      if (ks < 2 || kh == 0) {         // ks==2,kh==1 would read x k40..47 (OOB)
        const float* s = x + (trow + rw * 32 + l31) * IN_N + ks * 16 + kh * 8;
        a = cvt8(*reinterpret_cast<const float4*>(s),
                 *reinterpret_cast<const float4*>(s + 4));
      } else {
        a = (bf16x8){};
      }
      aR = MFMA32(a, g0, aR);
      aZ = MFMA32(a, g1, aZ);
      aI = MFMA32(a, g2, aI);
    }

    if (t < 3) issueH(t + 1);   // T14: next h tile global->reg under gh compute

    // ---- gh: 16 K-steps; A from hsw (swizzled), B from WG ----
    const int arow = rw * 32 + l31;
    const __bf16* arp = &hsw[arow * 256];
    const int ax = (arow & 7);
#pragma unroll
    for (int ks = 0; ks < 16; ++ks) {
      const int idx = ks * 2 + kh;
      const bf16x8 b0 = *reinterpret_cast<const bf16x8*>(&WG[(0 * 32 + idx) * 512 + colB * 8]);
      const bf16x8 b1 = *reinterpret_cast<const bf16x8*>(&WG[(1 * 32 + idx) * 512 + colB * 8]);
      const bf16x8 b2 = *reinterpret_cast<const bf16x8*>(&WG[(2 * 32 + idx) * 512 + colB * 8]);
      const bf16x8 a = *reinterpret_cast<const bf16x8*>(&arp[(idx ^ ax) << 3]);
      aR = MFMA32(a, b0, aR);
      aZ = MFMA32(a, b1, aZ);
      aH4 = MFMA32(a, b2, aH4);
    }

    __syncthreads();            // all hsw reads of tile t done

    if (t < 3) writeH();        // ds_writes overlap epilogue VALU below

    // ---- epilogue: fast gates, h_new store, pred partials; hv from h0 ----
    // C/D layout (verified m74/m101/v5): col = lane&31, row = (r&3)+8*(r>>2)+4*kh
    float ps[16];
#pragma unroll
    for (int r = 0; r < 16; ++r) {
      const int rowl = rw * 32 + (r & 3) + 8 * (r >> 2) + 4 * kh;
      const float rg = fsig(aR[r]);
      const float zg = fsig(aZ[r]);
      const float ng = ftanh(aI[r] + rg * aH4[r]);
      const float hv = h0[(trow + rowl) * H_N + hcol];   // L1/L2-hot
      const float hn = (1.f - zg) * ng + zg * hv;
      out[(size_t)B_N + (trow + rowl) * H_N + hcol] = hn;
      ps[r] = hn * wh;
    }
#pragma unroll
    for (int r = 0; r < 16; ++r) {
      float s = ps[r];
      s += __shfl_xor(s, 1);
      s += __shfl_xor(s, 2);
      s += __shfl_xor(s, 4);
      s += __shfl_xor(s, 8);
      s += __shfl_xor(s, 16);
      ps[r] = s;
    }
    if (l31 == 0) {   // lanes 0 and 32 -> 32 distinct rows via kh
#pragma unroll
      for (int r = 0; r < 16; ++r) {
        const int rowl = rw * 32 + (r & 3) + 8 * (r >> 2) + 4 * kh;
        atomicAdd(&out[trow + rowl], ps[r]);
      }
    }

    if (t < 3) __syncthreads();  // staged hsw(t+1) visible before next gh reads
  }
}

extern "C" void kernel_launch(void* const* d_in, const int* in_sizes, int n_in,
                              void* d_out, int out_size, void* d_ws, size_t ws_size,
                              hipStream_t stream) {
  const float* x     = (const float*)d_in[0];
  const float* h0    = (const float*)d_in[1];
  const float* Wp    = (const float*)d_in[2];
  const float* bp    = (const float*)d_in[3];
  const float* Wih   = (const float*)d_in[4];
  const float* Whh   = (const float*)d_in[5];
  const float* bih   = (const float*)d_in[6];
  const float* bhh   = (const float*)d_in[7];
  const float* Whead = (const float*)d_in[8];
  const float* bhead = (const float*)d_in[9];
  float* out = (float*)d_out;
  __bf16* wsb = (__bf16*)d_ws;

  prep<<<(PREP_N + 255) / 256, 256, 0, stream>>>(Wp, bp, Wih, Whh, bih, bhead, wsb, out);
  gru_v19<<<1024, 512, 0, stream>>>(x, h0, wsb, bhh, Whead, out);
}

// Round 18
// 237.701 us; speedup vs baseline: 1.2088x; 1.0339x over previous
//
#include <hip/hip_runtime.h>

#define B_N 131072
#define IN_N 40
#define H_N 256

typedef __bf16 bf16x8 __attribute__((ext_vector_type(8)));
typedef float f32x4 __attribute__((ext_vector_type(4)));

#define MFMA(a, b, c) __builtin_amdgcn_mfma_f32_16x16x32_bf16(a, b, c, 0, 0, 0)

// ws bf16 layout, EIGHTH-major (32 hcols per eighth):
//   eighth e: gh [3 g][32 idx][32 col][8 el]   (24576 elems, 48 KB)
//             gi [3 g][ 8 idx][32 col][8 el]   ( 6144 elems, 12 KB)
//   k = idx*8 + el; col = block-local hcol; gi zero for k>=40
// then f32 bfused[768] = b_ih + W_ih@b_proj
#define WSE 30720
#define WSBI (8 * WSE)                    // 245760
#define PREP_N (245760 + 768 + B_N)

__global__ void prep(const float* __restrict__ Wp, const float* __restrict__ bp,
                     const float* __restrict__ Wih, const float* __restrict__ Whh,
                     const float* __restrict__ bih, const float* __restrict__ bhead,
                     __bf16* __restrict__ wsb, float* __restrict__ out) {
  int i = blockIdx.x * 256 + threadIdx.x;
  if (i < WSBI) {
    const int e8 = i / WSE, r = i % WSE;
    if (r < 24576) {  // gh
      const int g = r >> 13, idx = (r >> 8) & 31, col = (r >> 3) & 31, el = r & 7;
      const int gatecol = g * 256 + e8 * 32 + col;
      wsb[i] = (__bf16)Whh[(size_t)gatecol * 256 + idx * 8 + el];
    } else {          // gi (fused W_ih @ W_proj), K padded 40->64
      const int rr = r - 24576;
      const int g = rr >> 11, idx = (rr >> 8) & 7, col = (rr >> 3) & 31, el = rr & 7;
      const int gatecol = g * 256 + e8 * 32 + col;
      const int k = idx * 8 + el;
      float v = 0.f;
      if (k < IN_N)
        for (int p = 0; p < 128; ++p)
          v += Wih[(size_t)gatecol * 128 + p] * Wp[p * IN_N + k];
      wsb[i] = (__bf16)v;
    }
  } else if (i < WSBI + 768) {
    const int g = i - WSBI;
    float v = bih[g];
    for (int p = 0; p < 128; ++p) v += Wih[g * 128 + p] * bp[p];
    ((float*)(wsb + WSBI))[g] = v;
  } else if (i < PREP_N) {
    out[i - (WSBI + 768)] = bhead[0];  // pred init = bias; waves atomicAdd partials
  }
}

__device__ __forceinline__ void gload16(const __bf16* g, __bf16* l) {
  __builtin_amdgcn_global_load_lds(
      (const __attribute__((address_space(1))) void*)g,
      (__attribute__((address_space(3))) void*)l, 16, 0, 0);
}

__device__ __forceinline__ bf16x8 cvt8(float4 a, float4 b) {
  bf16x8 u;
  u[0] = (__bf16)a.x; u[1] = (__bf16)a.y; u[2] = (__bf16)a.z; u[3] = (__bf16)a.w;
  u[4] = (__bf16)b.x; u[5] = (__bf16)b.y; u[6] = (__bf16)b.z; u[7] = (__bf16)b.w;
  return u;
}

// fast gate math (v17/v18-verified): v_exp_f32 computes 2^x; rcp not divide
__device__ __forceinline__ float fsig(float v) {
  return __builtin_amdgcn_rcpf(1.f + __builtin_amdgcn_exp2f(-1.44269504f * v));
}
__device__ __forceinline__ float ftanh(float u) {
  return 2.f * __builtin_amdgcn_rcpf(1.f + __builtin_amdgcn_exp2f(-2.88539008f * u)) - 1.f;
}

// 2048 blocks = 8 col-eighths x 256 row-groups; 512 thr = 8 waves (4rw x 2cw).
// 80 KB LDS/block -> TWO blocks/CU (16 waves/CU, 4/SIMD) with INDEPENDENT
// barriers: one block's epilogue/staging overlaps the other's LDS/MFMA phase.
// Persistent: gh weights (48KB) staged once; 8 tiles of 64 rows; h-tile 32KB
// swizzled; gi (x + weights) from global, transient regs. 2 barriers/tile.
__global__ __launch_bounds__(512, 4) void gru_v20(
    const float* __restrict__ x, const float* __restrict__ h0,
    const __bf16* __restrict__ wsb, const float* __restrict__ bhh,
    const float* __restrict__ Whead, float* __restrict__ out) {
  __shared__ __bf16 WG[24576];    // 49152 B: gh [3 g][32 idx][32 col][8]
  __shared__ __bf16 hsw[16384];   // 32768 B: [64 row][32 ci ^ (row&7)][8]
                                  // total 81920 B -> 2 blocks/CU

  const int tid = threadIdx.x;
  const int lane = tid & 63;
  const int w = tid >> 6;              // 0..7
  const int l15 = lane & 15;
  const int l4 = lane >> 4;
  const int rw = w >> 1, cw = w & 1;   // 4 row-bands x 2 col-groups

  // XCD-chunked: 8 eighth-siblings of a row-group adjacent -> h/x L2 reuse
  const int lin = (blockIdx.x & 7) * 256 + (blockIdx.x >> 3);
  const int e8 = lin & 7;
  const size_t row0 = (size_t)(lin >> 3) * 512;

  const int colE = cw * 16 + l15;      // block-local hcol 0..31
  const int hcol = e8 * 32 + colE;

  // ---- stage gh weights to LDS once (48 x 1KB async copies) ----
  const __bf16* wse = wsb + e8 * WSE;
#pragma unroll
  for (int j = 0; j < 6; ++j) {
    const int idx = w * 6 + j;         // wave-uniform, 0..47
    gload16(wse + idx * 512 + lane * 8, &WG[idx * 512]);
  }
  // gi weights stay in global (L2-hot, transient per tile)
  const __bf16* giWp = wse + 24576 + l4 * 256 + colE * 8;  // + g*2048 + ks*1024

  const float* bfused = (const float*)(wsb + WSBI);
  const float bR = bfused[hcol] + bhh[hcol];
  const float bZ = bfused[256 + hcol] + bhh[256 + hcol];
  const float bI = bfused[512 + hcol];
  const float bH = bhh[512 + hcol];
  const float wh = Whead[hcol];

  // ---- h staging: global -> reg (cvt at arrival, 16 VGPR) -> LDS ----
  bf16x8 hreg[4];
  auto issueH = [&](int t) {
    const float* hb = h0 + (row0 + (size_t)t * 64) * H_N;
#pragma unroll
    for (int j = 0; j < 4; ++j) {
      const int c = tid + j * 512;     // chunk 0..2047: row=c>>5, ci=c&31
      const float* s = hb + (size_t)(c >> 5) * H_N + (c & 31) * 8;
      hreg[j] = cvt8(*reinterpret_cast<const float4*>(s),
                     *reinterpret_cast<const float4*>(s + 4));
    }
  };
  auto writeH = [&]() {
#pragma unroll
    for (int j = 0; j < 4; ++j) {
      const int c = tid + j * 512;
      const int row = c >> 5, ci = c & 31;
      *reinterpret_cast<bf16x8*>(&hsw[row * 256 + ((ci ^ (row & 7)) << 3)]) = hreg[j];
    }
  };

  issueH(0);
  writeH();
  __syncthreads();   // WG (vmcnt drained at barrier) + h tile 0 visible

  for (int t = 0; t < 8; ++t) {
    const size_t trow = row0 + (size_t)t * 64;
    if (t < 7) issueH(t + 1);   // T14: next h tile global->reg under compute

    f32x4 aR = {bR, bR, bR, bR};
    f32x4 aZ = {bZ, bZ, bZ, bZ};
    f32x4 aI = {bI, bI, bI, bI};
    f32x4 aH4 = {bH, bH, bH, bH};

    // ---- gi: A from global x, B from global (transient regs) ----
#pragma unroll
    for (int ks = 0; ks < 2; ++ks) {
      const bf16x8 g0 = *reinterpret_cast<const bf16x8*>(giWp + 0 * 2048 + ks * 1024);
      const bf16x8 g1 = *reinterpret_cast<const bf16x8*>(giWp + 1 * 2048 + ks * 1024);
      const bf16x8 g2 = *reinterpret_cast<const bf16x8*>(giWp + 2 * 2048 + ks * 1024);
      bf16x8 a;
      if (ks == 0 || l4 == 0) {        // ks=1,l4>0 reads x k>=40 (OOB; W=0 there)
        const float* s = x + (trow + rw * 16 + l15) * IN_N + ks * 32 + l4 * 8;
        a = cvt8(*reinterpret_cast<const float4*>(s),
                 *reinterpret_cast<const float4*>(s + 4));
      } else {
        a = (bf16x8){};
      }
      aR = MFMA(a, g0, aR);
      aZ = MFMA(a, g1, aZ);
      aI = MFMA(a, g2, aI);
    }

    // ---- gh: A from hsw (swizzled), B from WG ----
    const int arow = rw * 16 + l15;
    const __bf16* arp = &hsw[arow * 256];
    const int ax = arow & 7;
#pragma unroll
    for (int ks = 0; ks < 8; ++ks) {
      const int bo = ks * 1024 + l4 * 256 + colE * 8;
      const bf16x8 b0 = *reinterpret_cast<const bf16x8*>(&WG[0 * 8192 + bo]);
      const bf16x8 b1 = *reinterpret_cast<const bf16x8*>(&WG[1 * 8192 + bo]);
      const bf16x8 b2 = *reinterpret_cast<const bf16x8*>(&WG[2 * 8192 + bo]);
      const bf16x8 a = *reinterpret_cast<const bf16x8*>(
          &arp[(((ks * 4 + l4) ^ ax)) << 3]);
      aR = MFMA(a, b0, aR);
      aZ = MFMA(a, b1, aZ);
      aH4 = MFMA(a, b2, aH4);
    }

    __syncthreads();            // all hsw reads of tile t done

    if (t < 7) writeH();        // ds_writes overlap epilogue VALU below

    // ---- epilogue: fast gates, h_new store, pred partials; hv from h0 ----
    float ps[4];
#pragma unroll
    for (int r = 0; r < 4; ++r) {
      const int rowl = rw * 16 + l4 * 4 + r;
      const float rg = fsig(aR[r]);
      const float zg = fsig(aZ[r]);
      const float ng = ftanh(aI[r] + rg * aH4[r]);
      const float hv = h0[(trow + rowl) * H_N + hcol];   // L1/L2-hot
      const float hn = (1.f - zg) * ng + zg * hv;
      out[(size_t)B_N + (trow + rowl) * H_N + hcol] = hn;
      ps[r] = hn * wh;
    }
#pragma unroll
    for (int r = 0; r < 4; ++r) {
      float s = ps[r];
      s += __shfl_xor(s, 1);
      s += __shfl_xor(s, 2);
      s += __shfl_xor(s, 4);
      s += __shfl_xor(s, 8);
      if (l15 == 0)
        atomicAdd(&out[trow + rw * 16 + l4 * 4 + r], s);
    }

    if (t < 7) __syncthreads();  // staged hsw(t+1) visible before next gh reads
  }
}

extern "C" void kernel_launch(void* const* d_in, const int* in_sizes, int n_in,
                              void* d_out, int out_size, void* d_ws, size_t ws_size,
                              hipStream_t stream) {
  const float* x     = (const float*)d_in[0];
  const float* h0    = (const float*)d_in[1];
  const float* Wp    = (const float*)d_in[2];
  const float* bp    = (const float*)d_in[3];
  const float* Wih   = (const float*)d_in[4];
  const float* Whh   = (const float*)d_in[5];
  const float* bih   = (const float*)d_in[6];
  const float* bhh   = (const float*)d_in[7];
  const float* Whead = (const float*)d_in[8];
  const float* bhead = (const float*)d_in[9];
  float* out = (float*)d_out;
  __bf16* wsb = (__bf16*)d_ws;

  prep<<<(PREP_N + 255) / 256, 256, 0, stream>>>(Wp, bp, Wih, Whh, bih, bhead, wsb, out);
  gru_v20<<<2048, 512, 0, stream>>>(x, h0, wsb, bhh, Whead, out);
}